// Round 3
// baseline (2157.399 us; speedup 1.0000x reference)
//
#include <hip/hip_runtime.h>

#define S_ 2048
#define H_ 2560
#define NH_ 20
#define NKV_ 5
#define HD_ 128
#define FF_ 6912
#define EPS_ 1e-5f

typedef __bf16 bf16;
typedef _Float16 f16;
typedef __bf16 bf16x8 __attribute__((ext_vector_type(8)));
typedef _Float16 f16x8 __attribute__((ext_vector_type(8)));
typedef float f32x4 __attribute__((ext_vector_type(4)));

// ---------------- reductions ----------------
__device__ inline float waveSum(float v) {
#pragma unroll
    for (int off = 32; off > 0; off >>= 1) v += __shfl_down(v, off);
    return v;
}
__device__ inline float waveMax(float v) {
#pragma unroll
    for (int off = 32; off > 0; off >>= 1) v = fmaxf(v, __shfl_down(v, off));
    return v;
}

// ---------------- weight |.| mean ----------------
__global__ void k_absmean(const float* __restrict__ w, int n, float* __restrict__ out) {
    __shared__ float red[4];
    float p = 0.f;
    for (int i = blockIdx.x * blockDim.x + threadIdx.x; i < n; i += gridDim.x * blockDim.x)
        p += fabsf(w[i]);
    p = waveSum(p);
    if ((threadIdx.x & 63) == 0) red[threadIdx.x >> 6] = p;
    __syncthreads();
    if (threadIdx.x == 0) atomicAdd(out, red[0] + red[1] + red[2] + red[3]);
}

// ---------------- weight ternary quant -> bf16 ----------------
__global__ void k_quant_w(const float* __restrict__ w, int n,
                          const float* __restrict__ sum, float inv_n,
                          bf16* __restrict__ wq) {
    float ws = fmaxf(sum[0] * inv_n, 1e-5f);
    for (int i = blockIdx.x * blockDim.x + threadIdx.x; i < n; i += gridDim.x * blockDim.x) {
        float q = rintf(w[i] / ws);
        q = fminf(fmaxf(q, -1.f), 1.f);
        wq[i] = (bf16)q;
    }
}

// ---------------- rmsnorm + activation int8 quant (as bf16 ints) ----------------
__global__ void k_rms_quant(const float* __restrict__ x, const float* __restrict__ wln,
                            int n, bf16* __restrict__ xq, float* __restrict__ a_scale) {
    extern __shared__ float sx[];
    float* red = sx + n;
    int row = blockIdx.x, tid = threadIdx.x;
    const float* xr = x + (size_t)row * n;
    float p = 0.f;
    for (int i = tid; i < n; i += 256) { float v = xr[i]; sx[i] = v; p += v * v; }
    p = waveSum(p);
    if ((tid & 63) == 0) red[tid >> 6] = p;
    __syncthreads();
    float ssum = red[0] + red[1] + red[2] + red[3];
    float rms = rsqrtf(ssum * (1.0f / n) + EPS_);
    __syncthreads();
    float mx = 0.f;
    for (int i = tid; i < n; i += 256) {
        float xv = sx[i] * rms * wln[i];
        sx[i] = xv;
        mx = fmaxf(mx, fabsf(xv));
    }
    mx = waveMax(mx);
    if ((tid & 63) == 0) red[tid >> 6] = mx;
    __syncthreads();
    float s = fmaxf(fmaxf(fmaxf(red[0], red[1]), fmaxf(red[2], red[3])), 1e-5f);
    if (tid == 0) a_scale[row] = s * (1.0f / 127.0f);
    float qs = 127.0f / s;
    for (int i = tid; i < n; i += 256) {
        float q = rintf(sx[i] * qs);
        q = fminf(fmaxf(q, -128.f), 127.f);
        xq[(size_t)row * n + i] = (bf16)q;
    }
}

// ---------------- bf16 MFMA GEMM ----------------
__global__ __launch_bounds__(256) void k_gemm_bt(
    const bf16* __restrict__ A, const bf16* __restrict__ Bw,
    int M, int N, int K,
    const float* __restrict__ a_scale, const float* __restrict__ ws_sum, float inv_n,
    const float* __restrict__ add, const float* __restrict__ gprev,
    float* __restrict__ outF) {
    __shared__ bf16 As[128 * 72];
    __shared__ bf16 Bs[128 * 72];
    int tid = threadIdx.x;
    int lane = tid & 63, w = tid >> 6;
    int quad = lane >> 4, l15 = lane & 15;
    int wm = w >> 1, wn = w & 1;
    int m0 = blockIdx.y * 128, n0 = blockIdx.x * 128;
    f32x4 acc[4][4] = {};
    int ar = tid >> 3, ac = (tid & 7) * 8;
    const bf16* Ag = A + (size_t)m0 * K;
    const bf16* Bg = Bw + (size_t)n0 * K;
    for (int kt = 0; kt < K; kt += 64) {
        __syncthreads();
#pragma unroll
        for (int ppp = 0; ppp < 4; ppp++) {
            int r = ar + ppp * 32;
            *(bf16x8*)&As[r * 72 + ac] = *(const bf16x8*)(Ag + (size_t)r * K + kt + ac);
            *(bf16x8*)&Bs[r * 72 + ac] = *(const bf16x8*)(Bg + (size_t)r * K + kt + ac);
        }
        __syncthreads();
#pragma unroll
        for (int kc = 0; kc < 2; kc++) {
            bf16x8 af[4], bfr[4];
#pragma unroll
            for (int i = 0; i < 4; i++)
                af[i] = *(const bf16x8*)&As[(wm * 64 + i * 16 + l15) * 72 + kc * 32 + quad * 8];
#pragma unroll
            for (int j = 0; j < 4; j++)
                bfr[j] = *(const bf16x8*)&Bs[(wn * 64 + j * 16 + l15) * 72 + kc * 32 + quad * 8];
#pragma unroll
            for (int i = 0; i < 4; i++)
#pragma unroll
                for (int j = 0; j < 4; j++)
                    acc[i][j] = __builtin_amdgcn_mfma_f32_16x16x32_bf16(af[i], bfr[j], acc[i][j], 0, 0, 0);
        }
    }
    float ws = fmaxf(ws_sum[0] * inv_n, 1e-5f);
#pragma unroll
    for (int i = 0; i < 4; i++) {
        int rowb = m0 + wm * 64 + i * 16 + quad * 4;
#pragma unroll
        for (int j = 0; j < 4; j++) {
            int col = n0 + wn * 64 + j * 16 + l15;
#pragma unroll
            for (int r = 0; r < 4; r++) {
                int row = rowb + r;
                float val = a_scale[row] * ws * acc[i][j][r];
                size_t off = (size_t)row * N + col;
                if (add) val += add[off];
                if (gprev) {
                    float gv = fmaxf(gprev[off], 0.f);
                    val = gv * gv * val;
                }
                outF[off] = val;
            }
        }
    }
}

// ---------------- RoPE (fp32 in -> split f16 hi/lo out) ----------------
__global__ void k_rope_split(const float* __restrict__ xin, f16* __restrict__ xh,
                             f16* __restrict__ xl, const float* __restrict__ cosp,
                             const float* __restrict__ sinp, int nh) {
    int idx = blockIdx.x * 256 + threadIdx.x;
    int d = idx & 63;
    int t = idx >> 6;
    int h = t % nh;
    int s = t / nh;
    size_t base = (size_t)s * (nh * HD_) + h * HD_;
    float x1 = xin[base + d], x2 = xin[base + d + 64];
    float c1 = cosp[s * HD_ + d], s1 = sinp[s * HD_ + d];
    float c2 = cosp[s * HD_ + d + 64], s2 = sinp[s * HD_ + d + 64];
    float y1 = x1 * c1 - x2 * s1;
    float y2 = x2 * c2 + x1 * s2;
    f16 h1 = (f16)y1, h2 = (f16)y2;
    xh[base + d] = h1;
    xl[base + d] = (f16)(y1 - (float)h1);
    xh[base + d + 64] = h2;
    xl[base + d + 64] = (f16)(y2 - (float)h2);
}

// ---------------- V transpose + split: [S][NKV*HD] f32 -> [NKV*HD][S] f16 hi/lo ----------------
__global__ void k_vtrans(const float* __restrict__ vf, f16* __restrict__ vth,
                         f16* __restrict__ vtl) {
    int col = blockIdx.x;                       // kvh*HD + d  (640 rows out)
    int s = blockIdx.y * 256 + threadIdx.x;
    float v = vf[(size_t)s * (NKV_ * HD_) + col];
    f16 h = (f16)v;
    vth[(size_t)col * S_ + s] = h;
    vtl[(size_t)col * S_ + s] = (f16)(v - (float)h);
}

// ---------------- flash attention, split-f16, causal, GQA 4:1, BARRIER-FREE ----------------
// 4 waves/block, each wave owns 16 q rows (TQ=64); K/V fragments streamed from global (L2).
// LDS only for the per-wave P C-layout->A-layout round-trip (no __syncthreads anywhere).
__global__ __launch_bounds__(256) void k_attn(
    const f16* __restrict__ qhp, const f16* __restrict__ qlp,
    const f16* __restrict__ khp, const f16* __restrict__ klp,
    const f16* __restrict__ vth, const f16* __restrict__ vtl,
    float* __restrict__ o) {
    __shared__ f16 Pth[4][16][40], Ptl[4][16][40];
    int tid = threadIdx.x;
    int w = tid >> 6, lane = tid & 63, quad = lane >> 4, l15 = lane & 15;
    int head = blockIdx.y;
    int qt = gridDim.x - 1 - blockIdx.x;        // longest (most K-tiles) first
    int q0 = qt * 64;
    int kvh = head >> 2;
    const int KVSTR = NKV_ * HD_;

    f16x8 qfh[4], qfl[4];
    {
        int qrow = q0 + w * 16 + l15;
        size_t qoff = (size_t)qrow * (NH_ * HD_) + head * HD_ + quad * 8;
#pragma unroll
        for (int kc = 0; kc < 4; kc++) {
            qfh[kc] = *(const f16x8*)(qhp + qoff + kc * 32);
            qfl[kc] = *(const f16x8*)(qlp + qoff + kc * 32);
        }
    }
    f32x4 oacc[8] = {};
    float m_i[4], l_i[4];
#pragma unroll
    for (int r = 0; r < 4; r++) { m_i[r] = -3.0e38f; l_i[r] = 0.f; }
    int nkt = (q0 + 64) >> 5;
    for (int kt = 0; kt < nkt; kt++) {
        int key0 = kt * 32;
        // K fragments direct from global (row-major [S][NKV][HD], contiguous in d)
        f16x8 kfh[2][4], kfl[2][4];
#pragma unroll
        for (int kn = 0; kn < 2; kn++)
#pragma unroll
            for (int kc = 0; kc < 4; kc++) {
                size_t ka = (size_t)(key0 + kn * 16 + l15) * KVSTR + kvh * HD_ + kc * 32 + quad * 8;
                kfh[kn][kc] = *(const f16x8*)(khp + ka);
                kfl[kn][kc] = *(const f16x8*)(klp + ka);
            }
        f32x4 sc[2] = {};
#pragma unroll
        for (int kn = 0; kn < 2; kn++)
#pragma unroll
            for (int kc = 0; kc < 4; kc++) {
                sc[kn] = __builtin_amdgcn_mfma_f32_16x16x32_f16(qfh[kc], kfh[kn][kc], sc[kn], 0, 0, 0);
                sc[kn] = __builtin_amdgcn_mfma_f32_16x16x32_f16(qfh[kc], kfl[kn][kc], sc[kn], 0, 0, 0);
                sc[kn] = __builtin_amdgcn_mfma_f32_16x16x32_f16(qfl[kc], kfh[kn][kc], sc[kn], 0, 0, 0);
            }
        const float scale = 0.08838834764831845f; // 1/sqrt(128)
#pragma unroll
        for (int r = 0; r < 4; r++) {
            int qr = q0 + w * 16 + quad * 4 + r;
            float s0 = sc[0][r] * scale, s1 = sc[1][r] * scale;
            if (key0 + l15 > qr) s0 = -1e30f;
            if (key0 + 16 + l15 > qr) s1 = -1e30f;
            float mx = fmaxf(s0, s1);
#pragma unroll
            for (int off = 8; off > 0; off >>= 1) mx = fmaxf(mx, __shfl_xor(mx, off));
            float mnew = fmaxf(m_i[r], mx);
            float alpha = expf(m_i[r] - mnew);
            m_i[r] = mnew;
            l_i[r] *= alpha;
#pragma unroll
            for (int dn = 0; dn < 8; dn++) oacc[dn][r] *= alpha;
            float p0 = expf(s0 - mnew), p1 = expf(s1 - mnew);
            l_i[r] += p0 + p1;
            f16 ph0 = (f16)p0, ph1 = (f16)p1;
            Pth[w][quad * 4 + r][l15] = ph0;
            Pth[w][quad * 4 + r][16 + l15] = ph1;
            Ptl[w][quad * 4 + r][l15] = (f16)(p0 - (float)ph0);
            Ptl[w][quad * 4 + r][16 + l15] = (f16)(p1 - (float)ph1);
        }
        // per-wave LDS round-trip: same wave wrote it, ds ops are ordered -> no barrier
        f16x8 pfh = *(const f16x8*)&Pth[w][l15][quad * 8];
        f16x8 pfl = *(const f16x8*)&Ptl[w][l15][quad * 8];
#pragma unroll
        for (int dn = 0; dn < 8; dn++) {
            size_t va = (size_t)kvh * HD_ * S_ + (size_t)(dn * 16 + l15) * S_ + key0 + quad * 8;
            f16x8 vfh = *(const f16x8*)(vth + va);
            f16x8 vfl = *(const f16x8*)(vtl + va);
            oacc[dn] = __builtin_amdgcn_mfma_f32_16x16x32_f16(pfh, vfh, oacc[dn], 0, 0, 0);
            oacc[dn] = __builtin_amdgcn_mfma_f32_16x16x32_f16(pfh, vfl, oacc[dn], 0, 0, 0);
            oacc[dn] = __builtin_amdgcn_mfma_f32_16x16x32_f16(pfl, vfh, oacc[dn], 0, 0, 0);
        }
    }
    float linv[4];
#pragma unroll
    for (int r = 0; r < 4; r++) {
        float lt = l_i[r];
#pragma unroll
        for (int off = 8; off > 0; off >>= 1) lt += __shfl_xor(lt, off);
        linv[r] = 1.0f / lt;
    }
#pragma unroll
    for (int dn = 0; dn < 8; dn++)
#pragma unroll
        for (int r = 0; r < 4; r++) {
            int row = q0 + w * 16 + quad * 4 + r;
            o[(size_t)row * (NH_ * HD_) + head * HD_ + dn * 16 + l15] = oacc[dn][r] * linv[r];
        }
}

extern "C" void kernel_launch(void* const* d_in, const int* in_sizes, int n_in,
                              void* d_out, int out_size, void* d_ws, size_t ws_size,
                              hipStream_t stream) {
    const float* hidden   = (const float*)d_in[0];
    const float* cosp     = (const float*)d_in[1];
    const float* sinp     = (const float*)d_in[2];
    const float* w_in_ln  = (const float*)d_in[3];
    const float* w_q      = (const float*)d_in[4];
    const float* w_k      = (const float*)d_in[5];
    const float* w_v      = (const float*)d_in[6];
    const float* w_o      = (const float*)d_in[7];
    const float* w_attn   = (const float*)d_in[8];
    const float* w_post   = (const float*)d_in[9];
    const float* w_gate   = (const float*)d_in[10];
    const float* w_up     = (const float*)d_in[11];
    const float* w_ffn    = (const float*)d_in[12];
    const float* w_down   = (const float*)d_in[13];
    float* out = (float*)d_out;

    const size_t SH = (size_t)S_ * H_;
    const size_t SKV = (size_t)S_ * NKV_ * HD_;

    char* p = (char*)d_ws;
    auto alloc = [&](size_t b) { char* r = p; p += (b + 255) & ~(size_t)255; return r; };
    float* sums   = (float*)alloc(64 * 4);
    float* ascale = (float*)alloc(S_ * 4);
    bf16* wqb     = (bf16*)alloc((size_t)FF_ * H_ * 2);  // 35.4 MB, reused per weight
    bf16* xq      = (bf16*)alloc(SH * 2);                // 10.5 MB
    bf16* xqf     = (bf16*)alloc((size_t)S_ * FF_ * 2);  // 28.3 MB
    float* hbuf   = (float*)alloc(SH * 4);               // 21 MB
    char* reg     = alloc(62914560);                     // union region
    // early phase layout
    float* q   = (float*)reg;                      // 21.0 MB
    float* kf  = (float*)(reg + 20971520);         // 5.2 MB
    float* vf  = (float*)(reg + 26214400);         // 5.2 MB
    f16* qhb   = (f16*)(reg + 31457280);           // 10.5 MB
    f16* qlb   = (f16*)(reg + 41943040);           // 10.5 MB
    f16* khb   = (f16*)(reg + 52428800);           // 2.6 MB
    f16* klb   = (f16*)(reg + 55050240);           // 2.6 MB
    f16* vthb  = (f16*)(reg + 57671680);           // 2.6 MB (transposed [NKV*HD][S])
    f16* vtlb  = (f16*)(reg + 60293120);           // 2.6 MB
    float* ob  = (float*)reg;                      // attention out, aliases q (dead)
    float* mbuf = (float*)reg;                     // FFN m f32 56.6 MB (late phase)

    hipMemsetAsync(sums, 0, 64 * 4, stream);
    const int nQ = NH_ * HD_ * H_, nKV = NKV_ * HD_ * H_, nG = FF_ * H_;
    k_absmean<<<512, 256, 0, stream>>>(w_q, nQ, sums + 0);
    k_absmean<<<512, 256, 0, stream>>>(w_k, nKV, sums + 1);
    k_absmean<<<512, 256, 0, stream>>>(w_v, nKV, sums + 2);
    k_absmean<<<512, 256, 0, stream>>>(w_o, nQ, sums + 3);
    k_absmean<<<512, 256, 0, stream>>>(w_gate, nG, sums + 4);
    k_absmean<<<512, 256, 0, stream>>>(w_up, nG, sums + 5);
    k_absmean<<<512, 256, 0, stream>>>(w_down, nG, sums + 6);

    // input norm + quant
    k_rms_quant<<<S_, 256, (H_ + 64) * 4, stream>>>(hidden, w_in_ln, H_, xq, ascale);

    // Q
    k_quant_w<<<2048, 256, 0, stream>>>(w_q, nQ, sums + 0, 1.0f / nQ, wqb);
    k_gemm_bt<<<dim3(NH_ * HD_ / 128, S_ / 128), 256, 0, stream>>>(
        xq, wqb, S_, NH_ * HD_, H_, ascale, sums + 0, 1.0f / nQ, nullptr, nullptr, q);
    // K
    k_quant_w<<<2048, 256, 0, stream>>>(w_k, nKV, sums + 1, 1.0f / nKV, wqb);
    k_gemm_bt<<<dim3(NKV_ * HD_ / 128, S_ / 128), 256, 0, stream>>>(
        xq, wqb, S_, NKV_ * HD_, H_, ascale, sums + 1, 1.0f / nKV, nullptr, nullptr, kf);
    // V
    k_quant_w<<<2048, 256, 0, stream>>>(w_v, nKV, sums + 2, 1.0f / nKV, wqb);
    k_gemm_bt<<<dim3(NKV_ * HD_ / 128, S_ / 128), 256, 0, stream>>>(
        xq, wqb, S_, NKV_ * HD_, H_, ascale, sums + 2, 1.0f / nKV, nullptr, nullptr, vf);

    // RoPE + split to hi/lo f16; V transpose+split
    k_rope_split<<<S_ * NH_ * 64 / 256, 256, 0, stream>>>(q, qhb, qlb, cosp, sinp, NH_);
    k_rope_split<<<S_ * NKV_ * 64 / 256, 256, 0, stream>>>(kf, khb, klb, cosp, sinp, NKV_);
    k_vtrans<<<dim3(NKV_ * HD_, S_ / 256), 256, 0, stream>>>(vf, vthb, vtlb);

    // attention (barrier-free; writes ob, aliases q which is dead)
    k_attn<<<dim3(S_ / 64, NH_), 256, 0, stream>>>(qhb, qlb, khb, klb, vthb, vtlb, ob);

    // o-proj (+ residual hidden) -> h
    k_rms_quant<<<S_, 256, (H_ + 64) * 4, stream>>>(ob, w_attn, H_, xq, ascale);
    k_quant_w<<<2048, 256, 0, stream>>>(w_o, nQ, sums + 3, 1.0f / nQ, wqb);
    k_gemm_bt<<<dim3(H_ / 128, S_ / 128), 256, 0, stream>>>(
        xq, wqb, S_, H_, NH_ * HD_, ascale, sums + 3, 1.0f / nQ, hidden, nullptr, hbuf);

    // post-ln + gate -> g (f32, in mbuf)
    k_rms_quant<<<S_, 256, (H_ + 64) * 4, stream>>>(hbuf, w_post, H_, xq, ascale);
    k_quant_w<<<4096, 256, 0, stream>>>(w_gate, nG, sums + 4, 1.0f / nG, wqb);
    k_gemm_bt<<<dim3(FF_ / 128, S_ / 128), 256, 0, stream>>>(
        xq, wqb, S_, FF_, H_, ascale, sums + 4, 1.0f / nG, nullptr, nullptr, mbuf);
    // up, fused epilogue m = relu(g)^2 * u, in-place over g
    k_quant_w<<<4096, 256, 0, stream>>>(w_up, nG, sums + 5, 1.0f / nG, wqb);
    k_gemm_bt<<<dim3(FF_ / 128, S_ / 128), 256, 0, stream>>>(
        xq, wqb, S_, FF_, H_, ascale, sums + 5, 1.0f / nG, nullptr, mbuf, mbuf);

    // ffn norm + quant (f32 m)
    k_rms_quant<<<S_, 256, (FF_ + 64) * 4, stream>>>(mbuf, w_ffn, FF_, xqf, ascale);

    // down (+ residual h) -> out
    k_quant_w<<<4096, 256, 0, stream>>>(w_down, nG, sums + 6, 1.0f / nG, wqb);
    k_gemm_bt<<<dim3(H_ / 128, S_ / 128), 256, 0, stream>>>(
        xqf, wqb, S_, H_, FF_, ascale, sums + 6, 1.0f / nG, hbuf, nullptr, out);
}

// Round 4
// 1428.855 us; speedup vs baseline: 1.5099x; 1.5099x over previous
//
#include <hip/hip_runtime.h>

#define S_ 2048
#define H_ 2560
#define NH_ 20
#define NKV_ 5
#define HD_ 128
#define FF_ 6912
#define EPS_ 1e-5f

typedef __bf16 bf16;
typedef _Float16 f16;
typedef __bf16 bf16x4 __attribute__((ext_vector_type(4)));
typedef __bf16 bf16x8 __attribute__((ext_vector_type(8)));
typedef _Float16 f16x8 __attribute__((ext_vector_type(8)));
typedef float f32x4 __attribute__((ext_vector_type(4)));

// ---------------- reductions ----------------
__device__ inline float waveSum(float v) {
#pragma unroll
    for (int off = 32; off > 0; off >>= 1) v += __shfl_down(v, off);
    return v;
}
__device__ inline float waveMax(float v) {
#pragma unroll
    for (int off = 32; off > 0; off >>= 1) v = fmaxf(v, __shfl_down(v, off));
    return v;
}

// ---------------- weight |.| mean (float4) ----------------
__global__ void k_absmean(const float* __restrict__ w, int n, float* __restrict__ out) {
    __shared__ float red[4];
    float p = 0.f;
    int n4 = n >> 2;
    const float4* w4 = (const float4*)w;
    for (int i = blockIdx.x * blockDim.x + threadIdx.x; i < n4; i += gridDim.x * blockDim.x) {
        float4 v = w4[i];
        p += fabsf(v.x) + fabsf(v.y) + fabsf(v.z) + fabsf(v.w);
    }
    p = waveSum(p);
    if ((threadIdx.x & 63) == 0) red[threadIdx.x >> 6] = p;
    __syncthreads();
    if (threadIdx.x == 0) atomicAdd(out, red[0] + red[1] + red[2] + red[3]);
}

// ---------------- weight ternary quant -> bf16 (8 elem/thread) ----------------
__global__ void k_quant_w(const float* __restrict__ w, int n,
                          const float* __restrict__ sum, float inv_n,
                          bf16* __restrict__ wq) {
    float ws = fmaxf(sum[0] * inv_n, 1e-5f);
    int n8 = n >> 3;
    const float4* w4 = (const float4*)w;
    bf16x8* wq8 = (bf16x8*)wq;
    for (int i = blockIdx.x * 256 + threadIdx.x; i < n8; i += gridDim.x * 256) {
        float4 a = w4[i * 2], b = w4[i * 2 + 1];
        bf16x8 o;
        o[0] = (bf16)fminf(fmaxf(rintf(a.x / ws), -1.f), 1.f);
        o[1] = (bf16)fminf(fmaxf(rintf(a.y / ws), -1.f), 1.f);
        o[2] = (bf16)fminf(fmaxf(rintf(a.z / ws), -1.f), 1.f);
        o[3] = (bf16)fminf(fmaxf(rintf(a.w / ws), -1.f), 1.f);
        o[4] = (bf16)fminf(fmaxf(rintf(b.x / ws), -1.f), 1.f);
        o[5] = (bf16)fminf(fmaxf(rintf(b.y / ws), -1.f), 1.f);
        o[6] = (bf16)fminf(fmaxf(rintf(b.z / ws), -1.f), 1.f);
        o[7] = (bf16)fminf(fmaxf(rintf(b.w / ws), -1.f), 1.f);
        wq8[i] = o;
    }
}

// ---------------- rmsnorm + activation int8 quant (vectorized) ----------------
__global__ void k_rms_quant(const float* __restrict__ x, const float* __restrict__ wln,
                            int n, bf16* __restrict__ xq, float* __restrict__ a_scale) {
    extern __shared__ float sx[];
    __shared__ float red[4];
    int row = blockIdx.x, tid = threadIdx.x;
    int n4 = n >> 2;
    const float4* xr = (const float4*)(x + (size_t)row * n);
    const float4* wl4 = (const float4*)wln;
    float4* sx4 = (float4*)sx;
    float p = 0.f;
    for (int i = tid; i < n4; i += 256) {
        float4 v = xr[i];
        sx4[i] = v;
        p += v.x * v.x + v.y * v.y + v.z * v.z + v.w * v.w;
    }
    p = waveSum(p);
    if ((tid & 63) == 0) red[tid >> 6] = p;
    __syncthreads();
    float rms = rsqrtf((red[0] + red[1] + red[2] + red[3]) * (1.0f / n) + EPS_);
    __syncthreads();
    float mx = 0.f;
    for (int i = tid; i < n4; i += 256) {
        float4 xv = sx4[i];
        float4 wv = wl4[i];
        xv.x *= rms * wv.x; xv.y *= rms * wv.y; xv.z *= rms * wv.z; xv.w *= rms * wv.w;
        sx4[i] = xv;
        mx = fmaxf(mx, fmaxf(fmaxf(fabsf(xv.x), fabsf(xv.y)), fmaxf(fabsf(xv.z), fabsf(xv.w))));
    }
    mx = waveMax(mx);
    if ((tid & 63) == 0) red[tid >> 6] = mx;
    __syncthreads();
    float s = fmaxf(fmaxf(fmaxf(red[0], red[1]), fmaxf(red[2], red[3])), 1e-5f);
    if (tid == 0) a_scale[row] = s * (1.0f / 127.0f);
    float qs = 127.0f / s;
    bf16x4* xo = (bf16x4*)(xq + (size_t)row * n);
    for (int i = tid; i < n4; i += 256) {
        float4 xv = sx4[i];
        bf16x4 o;
        o[0] = (bf16)fminf(fmaxf(rintf(xv.x * qs), -128.f), 127.f);
        o[1] = (bf16)fminf(fmaxf(rintf(xv.y * qs), -128.f), 127.f);
        o[2] = (bf16)fminf(fmaxf(rintf(xv.z * qs), -128.f), 127.f);
        o[3] = (bf16)fminf(fmaxf(rintf(xv.w * qs), -128.f), 127.f);
        xo[i] = o;
    }
}

// ---------------- bf16 MFMA GEMM (unchanged from R2) ----------------
__global__ __launch_bounds__(256) void k_gemm_bt(
    const bf16* __restrict__ A, const bf16* __restrict__ Bw,
    int M, int N, int K,
    const float* __restrict__ a_scale, const float* __restrict__ ws_sum, float inv_n,
    const float* __restrict__ add, const float* __restrict__ gprev,
    float* __restrict__ outF) {
    __shared__ bf16 As[128 * 72];
    __shared__ bf16 Bs[128 * 72];
    int tid = threadIdx.x;
    int lane = tid & 63, w = tid >> 6;
    int quad = lane >> 4, l15 = lane & 15;
    int wm = w >> 1, wn = w & 1;
    int m0 = blockIdx.y * 128, n0 = blockIdx.x * 128;
    f32x4 acc[4][4] = {};
    int ar = tid >> 3, ac = (tid & 7) * 8;
    const bf16* Ag = A + (size_t)m0 * K;
    const bf16* Bg = Bw + (size_t)n0 * K;
    for (int kt = 0; kt < K; kt += 64) {
        __syncthreads();
#pragma unroll
        for (int ppp = 0; ppp < 4; ppp++) {
            int r = ar + ppp * 32;
            *(bf16x8*)&As[r * 72 + ac] = *(const bf16x8*)(Ag + (size_t)r * K + kt + ac);
            *(bf16x8*)&Bs[r * 72 + ac] = *(const bf16x8*)(Bg + (size_t)r * K + kt + ac);
        }
        __syncthreads();
#pragma unroll
        for (int kc = 0; kc < 2; kc++) {
            bf16x8 af[4], bfr[4];
#pragma unroll
            for (int i = 0; i < 4; i++)
                af[i] = *(const bf16x8*)&As[(wm * 64 + i * 16 + l15) * 72 + kc * 32 + quad * 8];
#pragma unroll
            for (int j = 0; j < 4; j++)
                bfr[j] = *(const bf16x8*)&Bs[(wn * 64 + j * 16 + l15) * 72 + kc * 32 + quad * 8];
#pragma unroll
            for (int i = 0; i < 4; i++)
#pragma unroll
                for (int j = 0; j < 4; j++)
                    acc[i][j] = __builtin_amdgcn_mfma_f32_16x16x32_bf16(af[i], bfr[j], acc[i][j], 0, 0, 0);
        }
    }
    float ws = fmaxf(ws_sum[0] * inv_n, 1e-5f);
#pragma unroll
    for (int i = 0; i < 4; i++) {
        int rowb = m0 + wm * 64 + i * 16 + quad * 4;
#pragma unroll
        for (int j = 0; j < 4; j++) {
            int col = n0 + wn * 64 + j * 16 + l15;
#pragma unroll
            for (int r = 0; r < 4; r++) {
                int row = rowb + r;
                float val = a_scale[row] * ws * acc[i][j][r];
                size_t off = (size_t)row * N + col;
                if (add) val += add[off];
                if (gprev) {
                    float gv = fmaxf(gprev[off], 0.f);
                    val = gv * gv * val;
                }
                outF[off] = val;
            }
        }
    }
}

// ---------------- RoPE (fp32 in -> split f16 hi/lo out) ----------------
__global__ void k_rope_split(const float* __restrict__ xin, f16* __restrict__ xh,
                             f16* __restrict__ xl, const float* __restrict__ cosp,
                             const float* __restrict__ sinp, int nh) {
    int idx = blockIdx.x * 256 + threadIdx.x;
    int d = idx & 63;
    int t = idx >> 6;
    int h = t % nh;
    int s = t / nh;
    size_t base = (size_t)s * (nh * HD_) + h * HD_;
    float x1 = xin[base + d], x2 = xin[base + d + 64];
    float c1 = cosp[s * HD_ + d], s1 = sinp[s * HD_ + d];
    float c2 = cosp[s * HD_ + d + 64], s2 = sinp[s * HD_ + d + 64];
    float y1 = x1 * c1 - x2 * s1;
    float y2 = x2 * c2 + x1 * s2;
    f16 h1 = (f16)y1, h2 = (f16)y2;
    xh[base + d] = h1;
    xl[base + d] = (f16)(y1 - (float)h1);
    xh[base + d + 64] = h2;
    xl[base + d + 64] = (f16)(y2 - (float)h2);
}

// ---------------- V transpose+split via LDS tile: [S][640] f32 -> [640][S] f16 hi/lo ----------------
__global__ __launch_bounds__(256) void k_vtrans(const float* __restrict__ vf,
                                                f16* __restrict__ vth, f16* __restrict__ vtl) {
    __shared__ float tile[64][65];
    int c0 = blockIdx.x * 64;
    int s0 = blockIdx.y * 64;
    int t = threadIdx.x;
    int sl = t >> 2, cq = (t & 3) * 16;
#pragma unroll
    for (int i = 0; i < 16; i += 4)
        *(float4*)&tile[sl][cq + i] =
            *(const float4*)(vf + (size_t)(s0 + sl) * (NKV_ * HD_) + c0 + cq + i);
    __syncthreads();
    int cl = t >> 2, sq = (t & 3) * 16;
#pragma unroll
    for (int i = 0; i < 16; i += 8) {
        f16x8 hi, lo;
#pragma unroll
        for (int j = 0; j < 8; j++) {
            float v = tile[sq + i + j][cl];
            f16 h = (f16)v;
            hi[j] = h;
            lo[j] = (f16)(v - (float)h);
        }
        size_t off = (size_t)(c0 + cl) * S_ + s0 + sq + i;
        *(f16x8*)(vth + off) = hi;
        *(f16x8*)(vtl + off) = lo;
    }
}

// ---------------- flash attention, split-f16, causal, GQA 4:1 ----------------
// R2 structure (coop LDS staging, 2 barriers/tile) with: V staged from pre-transposed
// global via coalesced b128 (no scatter -> no conflicts), longest-first dispatch.
__global__ __launch_bounds__(256) void k_attn(
    const f16* __restrict__ qhp, const f16* __restrict__ qlp,
    const f16* __restrict__ khp, const f16* __restrict__ klp,
    const f16* __restrict__ vtg_h, const f16* __restrict__ vtg_l,
    float* __restrict__ o) {
    __shared__ f16 Kth[32][136], Ktl[32][136];
    __shared__ f16 Vth[128][40], Vtl[128][40];
    __shared__ f16 Pth[4][16][40], Ptl[4][16][40];
    int tid = threadIdx.x;
    int w = tid >> 6, lane = tid & 63, quad = lane >> 4, l15 = lane & 15;
    int head = blockIdx.y;
    int qt = gridDim.x - 1 - blockIdx.x;   // longest-first
    int q0 = qt * 64;
    int kvh = head >> 2;
    const int KVSTR = NKV_ * HD_;

    f16x8 qfh[4], qfl[4];
    {
        int qrow = q0 + w * 16 + l15;
        size_t qoff = (size_t)qrow * (NH_ * HD_) + head * HD_ + quad * 8;
#pragma unroll
        for (int kc = 0; kc < 4; kc++) {
            qfh[kc] = *(const f16x8*)(qhp + qoff + kc * 32);
            qfl[kc] = *(const f16x8*)(qlp + qoff + kc * 32);
        }
    }
    f32x4 oacc[8] = {};
    float m_i[4], l_i[4];
#pragma unroll
    for (int r = 0; r < 4; r++) { m_i[r] = -3.0e38f; l_i[r] = 0.f; }
    int sr = tid >> 3, scb = (tid & 7) * 16;
    int vd = tid >> 1, vh16 = (tid & 1) * 16;
    int nkt = (q0 + 64) >> 5;
    for (int kt = 0; kt < nkt; kt++) {
        int key0 = kt * 32;
        __syncthreads();
        {
            size_t koff = (size_t)(key0 + sr) * KVSTR + kvh * HD_ + scb;
            *(f16x8*)&Kth[sr][scb] = *(const f16x8*)(khp + koff);
            *(f16x8*)&Kth[sr][scb + 8] = *(const f16x8*)(khp + koff + 8);
            *(f16x8*)&Ktl[sr][scb] = *(const f16x8*)(klp + koff);
            *(f16x8*)&Ktl[sr][scb + 8] = *(const f16x8*)(klp + koff + 8);
            size_t voff = (size_t)(kvh * HD_ + vd) * S_ + key0 + vh16;
            *(f16x8*)&Vth[vd][vh16] = *(const f16x8*)(vtg_h + voff);
            *(f16x8*)&Vth[vd][vh16 + 8] = *(const f16x8*)(vtg_h + voff + 8);
            *(f16x8*)&Vtl[vd][vh16] = *(const f16x8*)(vtg_l + voff);
            *(f16x8*)&Vtl[vd][vh16 + 8] = *(const f16x8*)(vtg_l + voff + 8);
        }
        __syncthreads();
        f32x4 sc[2] = {};
#pragma unroll
        for (int kn = 0; kn < 2; kn++)
#pragma unroll
            for (int kc = 0; kc < 4; kc++) {
                f16x8 kfh = *(const f16x8*)&Kth[kn * 16 + l15][kc * 32 + quad * 8];
                f16x8 kfl = *(const f16x8*)&Ktl[kn * 16 + l15][kc * 32 + quad * 8];
                sc[kn] = __builtin_amdgcn_mfma_f32_16x16x32_f16(qfh[kc], kfh, sc[kn], 0, 0, 0);
                sc[kn] = __builtin_amdgcn_mfma_f32_16x16x32_f16(qfh[kc], kfl, sc[kn], 0, 0, 0);
                sc[kn] = __builtin_amdgcn_mfma_f32_16x16x32_f16(qfl[kc], kfh, sc[kn], 0, 0, 0);
            }
        const float scale = 0.08838834764831845f; // 1/sqrt(128)
#pragma unroll
        for (int r = 0; r < 4; r++) {
            int qr = q0 + w * 16 + quad * 4 + r;
            float s0 = sc[0][r] * scale, s1 = sc[1][r] * scale;
            if (key0 + l15 > qr) s0 = -1e30f;
            if (key0 + 16 + l15 > qr) s1 = -1e30f;
            float mx = fmaxf(s0, s1);
#pragma unroll
            for (int off = 8; off > 0; off >>= 1) mx = fmaxf(mx, __shfl_xor(mx, off));
            float mnew = fmaxf(m_i[r], mx);
            float alpha = expf(m_i[r] - mnew);
            m_i[r] = mnew;
            l_i[r] *= alpha;
#pragma unroll
            for (int dn = 0; dn < 8; dn++) oacc[dn][r] *= alpha;
            float p0 = expf(s0 - mnew), p1 = expf(s1 - mnew);
            l_i[r] += p0 + p1;
            f16 ph0 = (f16)p0, ph1 = (f16)p1;
            Pth[w][quad * 4 + r][l15] = ph0;
            Pth[w][quad * 4 + r][16 + l15] = ph1;
            Ptl[w][quad * 4 + r][l15] = (f16)(p0 - (float)ph0);
            Ptl[w][quad * 4 + r][16 + l15] = (f16)(p1 - (float)ph1);
        }
        // per-wave LDS round-trip (same wave wrote it; ds ops ordered within wave)
        f16x8 pfh = *(const f16x8*)&Pth[w][l15][quad * 8];
        f16x8 pfl = *(const f16x8*)&Ptl[w][l15][quad * 8];
#pragma unroll
        for (int dn = 0; dn < 8; dn++) {
            f16x8 vfh = *(const f16x8*)&Vth[dn * 16 + l15][quad * 8];
            f16x8 vfl = *(const f16x8*)&Vtl[dn * 16 + l15][quad * 8];
            oacc[dn] = __builtin_amdgcn_mfma_f32_16x16x32_f16(pfh, vfh, oacc[dn], 0, 0, 0);
            oacc[dn] = __builtin_amdgcn_mfma_f32_16x16x32_f16(pfh, vfl, oacc[dn], 0, 0, 0);
            oacc[dn] = __builtin_amdgcn_mfma_f32_16x16x32_f16(pfl, vfh, oacc[dn], 0, 0, 0);
        }
    }
    float linv[4];
#pragma unroll
    for (int r = 0; r < 4; r++) {
        float lt = l_i[r];
#pragma unroll
        for (int off = 8; off > 0; off >>= 1) lt += __shfl_xor(lt, off);
        linv[r] = 1.0f / lt;
    }
#pragma unroll
    for (int dn = 0; dn < 8; dn++)
#pragma unroll
        for (int r = 0; r < 4; r++) {
            int row = q0 + w * 16 + quad * 4 + r;
            o[(size_t)row * (NH_ * HD_) + head * HD_ + dn * 16 + l15] = oacc[dn][r] * linv[r];
        }
}

extern "C" void kernel_launch(void* const* d_in, const int* in_sizes, int n_in,
                              void* d_out, int out_size, void* d_ws, size_t ws_size,
                              hipStream_t stream) {
    const float* hidden   = (const float*)d_in[0];
    const float* cosp     = (const float*)d_in[1];
    const float* sinp     = (const float*)d_in[2];
    const float* w_in_ln  = (const float*)d_in[3];
    const float* w_q      = (const float*)d_in[4];
    const float* w_k      = (const float*)d_in[5];
    const float* w_v      = (const float*)d_in[6];
    const float* w_o      = (const float*)d_in[7];
    const float* w_attn   = (const float*)d_in[8];
    const float* w_post   = (const float*)d_in[9];
    const float* w_gate   = (const float*)d_in[10];
    const float* w_up     = (const float*)d_in[11];
    const float* w_ffn    = (const float*)d_in[12];
    const float* w_down   = (const float*)d_in[13];
    float* out = (float*)d_out;

    const size_t SH = (size_t)S_ * H_;

    char* p = (char*)d_ws;
    auto alloc = [&](size_t b) { char* r = p; p += (b + 255) & ~(size_t)255; return r; };
    float* sums   = (float*)alloc(64 * 4);
    float* ascale = (float*)alloc(S_ * 4);
    bf16* wqb     = (bf16*)alloc((size_t)FF_ * H_ * 2);  // 35.4 MB, reused per weight
    bf16* xq      = (bf16*)alloc(SH * 2);                // 10.5 MB
    bf16* xqf     = (bf16*)alloc((size_t)S_ * FF_ * 2);  // 28.3 MB
    float* hbuf   = (float*)alloc(SH * 4);               // 21 MB
    char* reg     = alloc(62914560);                     // union region
    // early phase layout
    float* q   = (float*)reg;                      // 21.0 MB
    float* kf  = (float*)(reg + 20971520);         // 5.2 MB
    float* vf  = (float*)(reg + 26214400);         // 5.2 MB
    f16* qhb   = (f16*)(reg + 31457280);           // 10.5 MB
    f16* qlb   = (f16*)(reg + 41943040);           // 10.5 MB
    f16* khb   = (f16*)(reg + 52428800);           // 2.6 MB
    f16* klb   = (f16*)(reg + 55050240);           // 2.6 MB
    f16* vthb  = (f16*)(reg + 57671680);           // 2.6 MB (transposed [640][S])
    f16* vtlb  = (f16*)(reg + 60293120);           // 2.6 MB
    float* ob  = (float*)reg;                      // attention out, aliases q (dead)
    float* mbuf = (float*)reg;                     // FFN m f32 56.6 MB (late phase)

    hipMemsetAsync(sums, 0, 64 * 4, stream);
    const int nQ = NH_ * HD_ * H_, nKV = NKV_ * HD_ * H_, nG = FF_ * H_;
    k_absmean<<<512, 256, 0, stream>>>(w_q, nQ, sums + 0);
    k_absmean<<<512, 256, 0, stream>>>(w_k, nKV, sums + 1);
    k_absmean<<<512, 256, 0, stream>>>(w_v, nKV, sums + 2);
    k_absmean<<<512, 256, 0, stream>>>(w_o, nQ, sums + 3);
    k_absmean<<<512, 256, 0, stream>>>(w_gate, nG, sums + 4);
    k_absmean<<<512, 256, 0, stream>>>(w_up, nG, sums + 5);
    k_absmean<<<512, 256, 0, stream>>>(w_down, nG, sums + 6);

    // input norm + quant
    k_rms_quant<<<S_, 256, (H_ + 64) * 4, stream>>>(hidden, w_in_ln, H_, xq, ascale);

    // Q
    k_quant_w<<<3200, 256, 0, stream>>>(w_q, nQ, sums + 0, 1.0f / nQ, wqb);
    k_gemm_bt<<<dim3(NH_ * HD_ / 128, S_ / 128), 256, 0, stream>>>(
        xq, wqb, S_, NH_ * HD_, H_, ascale, sums + 0, 1.0f / nQ, nullptr, nullptr, q);
    // K
    k_quant_w<<<800, 256, 0, stream>>>(w_k, nKV, sums + 1, 1.0f / nKV, wqb);
    k_gemm_bt<<<dim3(NKV_ * HD_ / 128, S_ / 128), 256, 0, stream>>>(
        xq, wqb, S_, NKV_ * HD_, H_, ascale, sums + 1, 1.0f / nKV, nullptr, nullptr, kf);
    // V
    k_quant_w<<<800, 256, 0, stream>>>(w_v, nKV, sums + 2, 1.0f / nKV, wqb);
    k_gemm_bt<<<dim3(NKV_ * HD_ / 128, S_ / 128), 256, 0, stream>>>(
        xq, wqb, S_, NKV_ * HD_, H_, ascale, sums + 2, 1.0f / nKV, nullptr, nullptr, vf);

    // RoPE + split to hi/lo f16; V transpose+split (LDS tile, coalesced both sides)
    k_rope_split<<<S_ * NH_ * 64 / 256, 256, 0, stream>>>(q, qhb, qlb, cosp, sinp, NH_);
    k_rope_split<<<S_ * NKV_ * 64 / 256, 256, 0, stream>>>(kf, khb, klb, cosp, sinp, NKV_);
    k_vtrans<<<dim3(NKV_ * HD_ / 64, S_ / 64), 256, 0, stream>>>(vf, vthb, vtlb);

    // attention (writes ob, aliases q which is dead)
    k_attn<<<dim3(S_ / 64, NH_), 256, 0, stream>>>(qhb, qlb, khb, klb, vthb, vtlb, ob);

    // o-proj (+ residual hidden) -> h
    k_rms_quant<<<S_, 256, (H_ + 64) * 4, stream>>>(ob, w_attn, H_, xq, ascale);
    k_quant_w<<<3200, 256, 0, stream>>>(w_o, nQ, sums + 3, 1.0f / nQ, wqb);
    k_gemm_bt<<<dim3(H_ / 128, S_ / 128), 256, 0, stream>>>(
        xq, wqb, S_, H_, NH_ * HD_, ascale, sums + 3, 1.0f / nQ, hidden, nullptr, hbuf);

    // post-ln + gate -> g (f32, in mbuf)
    k_rms_quant<<<S_, 256, (H_ + 64) * 4, stream>>>(hbuf, w_post, H_, xq, ascale);
    k_quant_w<<<8640, 256, 0, stream>>>(w_gate, nG, sums + 4, 1.0f / nG, wqb);
    k_gemm_bt<<<dim3(FF_ / 128, S_ / 128), 256, 0, stream>>>(
        xq, wqb, S_, FF_, H_, ascale, sums + 4, 1.0f / nG, nullptr, nullptr, mbuf);
    // up, fused epilogue m = relu(g)^2 * u, in-place over g
    k_quant_w<<<8640, 256, 0, stream>>>(w_up, nG, sums + 5, 1.0f / nG, wqb);
    k_gemm_bt<<<dim3(FF_ / 128, S_ / 128), 256, 0, stream>>>(
        xq, wqb, S_, FF_, H_, ascale, sums + 5, 1.0f / nG, nullptr, mbuf, mbuf);

    // ffn norm + quant (f32 m)
    k_rms_quant<<<S_, 256, (FF_ + 64) * 4, stream>>>(mbuf, w_ffn, FF_, xqf, ascale);

    // down (+ residual h) -> out
    k_quant_w<<<8640, 256, 0, stream>>>(w_down, nG, sums + 6, 1.0f / nG, wqb);
    k_gemm_bt<<<dim3(H_ / 128, S_ / 128), 256, 0, stream>>>(
        xqf, wqb, S_, H_, FF_, ascale, sums + 6, 1.0f / nG, hbuf, nullptr, out);
}